// Round 19
// baseline (212.136 us; speedup 1.0000x reference)
//
#include <hip/hip_runtime.h>
#include <hip/hip_bf16.h>
#include <cstdint>
#include <cstddef>

typedef __attribute__((ext_vector_type(8))) short short8;
typedef __attribute__((ext_vector_type(4))) float floatx4;
typedef __attribute__((ext_vector_type(16))) float floatx16;
typedef unsigned short u16;

__device__ __forceinline__ u16 f2bf(float f) {
  unsigned u = __float_as_uint(f);
  u += 0x7FFFu + ((u >> 16) & 1u);
  return (u16)(u >> 16);
}

__device__ __forceinline__ unsigned cvt_pk_bf16(float a, float b) {
  unsigned r;
  asm("v_cvt_pk_bf16_f32 %0, %1, %2" : "=v"(r) : "v"(a), "v"(b));
  return r;
}

// raw 2^x. TRANS op: builtin so the compiler handles the TRANS->VALU hazard.
__device__ __forceinline__ float fexp2(float x) {
#if __has_builtin(__builtin_amdgcn_exp2f)
  return __builtin_amdgcn_exp2f(x);
#else
  float r;
  asm("v_exp_f32 %0, %1\n\ts_nop 1" : "=v"(r) : "v"(x));
  return r;
#endif
}

__device__ __forceinline__ float frcp(float x) {
#if __has_builtin(__builtin_amdgcn_rcpf)
  return __builtin_amdgcn_rcpf(x);
#else
  float r;
  asm("v_rcp_f32 %0, %1\n\ts_nop 1" : "=v"(r) : "v"(x));
  return r;
#endif
}

// async global -> LDS, 16B per lane. LDS dest = wave-uniform base + lane*16.
__device__ __forceinline__ void gload16(const u16* g, u16* l) {
  __builtin_amdgcn_global_load_lds(
      (const __attribute__((address_space(1))) void*)g,
      (__attribute__((address_space(3))) void*)l, 16, 0, 0);
}

__device__ __forceinline__ void phase_barrier() {
  __builtin_amdgcn_sched_barrier(0);
  __builtin_amdgcn_s_barrier();
  __builtin_amdgcn_sched_barrier(0);
}

#define MFMA16(a, b, c) __builtin_amdgcn_mfma_f32_16x16x32_bf16((a), (b), (c), 0, 0, 0)

// ---------------- f32 -> bf16 convert: 3 buffers in one launch ----------------
__global__ void cvt3_kernel(const float* __restrict__ a, u16* __restrict__ oa, int na4,
                            const float* __restrict__ b, u16* __restrict__ ob, int nb4,
                            const float* __restrict__ c, u16* __restrict__ oc, int nc4) {
  int i = blockIdx.x * blockDim.x + threadIdx.x;
  int stride = gridDim.x * blockDim.x;
  int ntot = na4 + nb4 + nc4;
  for (int idx = i; idx < ntot; idx += stride) {
    const float* src; u16* dst; int j = idx;
    if (j < na4)            { src = a; dst = oa; }
    else if (j < na4 + nb4) { src = b; dst = ob; j -= na4; }
    else                    { src = c; dst = oc; j -= na4 + nb4; }
    float4 v = reinterpret_cast<const float4*>(src)[j];
    ushort4 o = make_ushort4(f2bf(v.x), f2bf(v.y), f2bf(v.z), f2bf(v.w));
    reinterpret_cast<ushort4*>(dst)[j] = o;
  }
}

// ------ C = A @ B^T + bias, 256x256 tile, BK=64, 8-phase schedule (R16 best) ------
template<bool OUTF32>
__global__ __launch_bounds__(512) void gemm_bt256_8p(
    const u16* __restrict__ A, const u16* __restrict__ B,
    const float* __restrict__ bias, void* __restrict__ Cout,
    int M, int N, int K, int qcols, float qscale)
{
  __shared__ u16 As[4 * 8192];   // 64 KB: [slot][half] 128x64
  __shared__ u16 Bs[4 * 8192];   // 64 KB
  const int tid = threadIdx.x;
  const int lane = tid & 63, w = tid >> 6;          // 8 waves
  const int l15 = lane & 15, lhi = lane >> 4;
  const int wm = w >> 2, wn = w & 3;                // 2M x 4N, wave tile 128x64

  const int mblocks = M >> 8;        // %8 == 0
  const int nb = N >> 8;
  const int bid = blockIdx.x;
  const int xcd = bid & 7;
  const int local = bid >> 3;
  const int mpx = mblocks >> 3;
  const int m0 = (xcd * mpx + local / nb) << 8;
  const int n0 = (local % nb) << 8;

  const int trow = tid >> 3;                         // 0..63
  const int cg8 = ((tid & 7) ^ ((tid >> 4) & 7)) * 8;  // swizzled 8-elem chunk
  const u16* aS = A + (size_t)(m0 + trow) * K + cg8;
  const u16* bS = B + (size_t)(n0 + trow) * K + cg8;
  const int ksteps = K >> 6;   // BK = 64

  const int x7 = (l15 >> 1) & 7;
  const int ko0 = l15 * 64 + (lhi ^ x7) * 8;        // kk = 0
  const int ko1 = l15 * 64 + ((4 + lhi) ^ x7) * 8;  // kk = 1
  const int brow = (wn & 1) * 64;                   // band within B region

  floatx4 acc[8][4] = {};

#define STG(matS, lds, v, h) do { \
    gload16((matS) + (size_t)((h) * 128) * K + (size_t)(v) * 64, \
            (lds) + ((((v) & 1) * 2 + (h)) * 8192) + w * 512); \
    gload16((matS) + (size_t)((h) * 128 + 64) * K + (size_t)(v) * 64, \
            (lds) + ((((v) & 1) * 2 + (h)) * 8192) + 4096 + w * 512); \
  } while (0)

  STG(aS, As, 0, 0); STG(aS, As, 0, 1);
  STG(bS, Bs, 0, 0); STG(bS, Bs, 0, 1);
  if (ksteps > 1) {
    STG(bS, Bs, 1, 0); STG(bS, Bs, 1, 1);
    asm volatile("s_waitcnt vmcnt(4)" ::: "memory");   // tile 0 resident
  } else {
    asm volatile("s_waitcnt vmcnt(0)" ::: "memory");
  }
  phase_barrier();

  for (int u = 0; u < ksteps; ++u) {
    const int so = (u & 1) * 16384;
    const u16* Ab = As + so + wm * 8192;
    const u16* Bb = Bs + so + (wn >> 1) * 8192;
    short8 af[4][2], bf[4][2];

    // ---- phase 1 (qm=0,qn=0): read af[0..3], bf[0..1]; stage A.h0(u+1)
#pragma unroll
    for (int i = 0; i < 4; ++i) {
      af[i][0] = *reinterpret_cast<const short8*>(Ab + (i * 16) * 64 + ko0);
      af[i][1] = *reinterpret_cast<const short8*>(Ab + (i * 16) * 64 + ko1);
    }
#pragma unroll
    for (int j = 0; j < 2; ++j) {
      bf[j][0] = *reinterpret_cast<const short8*>(Bb + (brow + j * 16) * 64 + ko0);
      bf[j][1] = *reinterpret_cast<const short8*>(Bb + (brow + j * 16) * 64 + ko1);
    }
    if (u + 1 < ksteps) STG(aS, As, u + 1, 0);
    phase_barrier();
    __builtin_amdgcn_s_setprio(1);
#pragma unroll
    for (int i = 0; i < 4; ++i)
#pragma unroll
      for (int j = 0; j < 2; ++j) {
        acc[i][j] = MFMA16(af[i][0], bf[j][0], acc[i][j]);
        acc[i][j] = MFMA16(af[i][1], bf[j][1], acc[i][j]);
      }
    __builtin_amdgcn_s_setprio(0);
    phase_barrier();

    // ---- phase 2 (qm=0,qn=1): read bf[2..3]; stage A.h1(u+1)
#pragma unroll
    for (int j = 2; j < 4; ++j) {
      bf[j][0] = *reinterpret_cast<const short8*>(Bb + (brow + 32 + (j - 2) * 16) * 64 + ko0);
      bf[j][1] = *reinterpret_cast<const short8*>(Bb + (brow + 32 + (j - 2) * 16) * 64 + ko1);
    }
    if (u + 1 < ksteps) STG(aS, As, u + 1, 1);
    phase_barrier();
    __builtin_amdgcn_s_setprio(1);
#pragma unroll
    for (int i = 0; i < 4; ++i)
#pragma unroll
      for (int j = 2; j < 4; ++j) {
        acc[i][j] = MFMA16(af[i][0], bf[j][0], acc[i][j]);
        acc[i][j] = MFMA16(af[i][1], bf[j][1], acc[i][j]);
      }
    __builtin_amdgcn_s_setprio(0);
    phase_barrier();

    // ---- phase 3 (qm=1,qn=0): read af rows 64..127; stage B.h0(u+2)
#pragma unroll
    for (int i = 0; i < 4; ++i) {
      af[i][0] = *reinterpret_cast<const short8*>(Ab + (64 + i * 16) * 64 + ko0);
      af[i][1] = *reinterpret_cast<const short8*>(Ab + (64 + i * 16) * 64 + ko1);
    }
    if (u + 2 < ksteps) STG(bS, Bs, u + 2, 0);
    phase_barrier();
    __builtin_amdgcn_s_setprio(1);
#pragma unroll
    for (int i = 0; i < 4; ++i)
#pragma unroll
      for (int j = 0; j < 2; ++j) {
        acc[4 + i][j] = MFMA16(af[i][0], bf[j][0], acc[4 + i][j]);
        acc[4 + i][j] = MFMA16(af[i][1], bf[j][1], acc[4 + i][j]);
      }
    __builtin_amdgcn_s_setprio(0);
    phase_barrier();

    // ---- phase 4 (qm=1,qn=1): stage B.h1(u+2); boundary vmcnt
    if (u + 2 < ksteps) STG(bS, Bs, u + 2, 1);
    phase_barrier();
    __builtin_amdgcn_s_setprio(1);
#pragma unroll
    for (int i = 0; i < 4; ++i)
#pragma unroll
      for (int j = 2; j < 4; ++j) {
        acc[4 + i][j] = MFMA16(af[i][0], bf[j][0], acc[4 + i][j]);
        acc[4 + i][j] = MFMA16(af[i][1], bf[j][1], acc[4 + i][j]);
      }
    __builtin_amdgcn_s_setprio(0);
    if (u + 1 < ksteps) {
      if (u + 2 < ksteps) asm volatile("s_waitcnt vmcnt(4)" ::: "memory");
      else                asm volatile("s_waitcnt vmcnt(0)" ::: "memory");
    }
    phase_barrier();
  }
#undef STG

#pragma unroll
  for (int i = 0; i < 8; ++i)
#pragma unroll
    for (int j = 0; j < 4; ++j) {
      int row = m0 + wm * 128 + i * 16 + lhi * 4;
      int col = n0 + wn * 64 + j * 16 + l15;
      float bv = bias[col];
      float sc = (col < qcols) ? qscale : 1.0f;
#pragma unroll
      for (int r = 0; r < 4; ++r) {
        float v = (acc[i][j][r] + bv) * sc;
        if (OUTF32) reinterpret_cast<float*>(Cout)[(size_t)(row + r) * N + col] = v;
        else        reinterpret_cast<u16*>(Cout)[(size_t)(row + r) * N + col] = f2bf(v);
      }
    }
}

// ---------------- V transpose: qkv V-part -> vt[(b*12+h)*64 + d][s] ----------------
__global__ __launch_bounds__(256) void vtrans_kernel(
    const u16* __restrict__ qkv, u16* __restrict__ vt)
{
  __shared__ u16 T[64][72];
  const int idx = blockIdx.x;
  const int st = idx & 15;
  const int bh = idx >> 4;
  const int b = bh / 12, h = bh % 12;
  const int t = threadIdx.x;
  const int r2 = t >> 3, c8 = (t & 7) * 8;

  const u16* src = qkv + ((size_t)(b * 1024 + st * 64)) * 2304 + 1536 + h * 64;
#pragma unroll
  for (int rr = 0; rr < 2; ++rr) {
    int s = rr * 32 + r2;
    short8 v = *reinterpret_cast<const short8*>(src + (size_t)s * 2304 + c8);
    *reinterpret_cast<short8*>(&T[s][c8]) = v;
  }
  __syncthreads();
  u16* dst = vt + (size_t)bh * 64 * 1024 + st * 64;
#pragma unroll
  for (int rr = 0; rr < 2; ++rr) {
    int d = rr * 32 + r2;
    short8 o;
#pragma unroll
    for (int j = 0; j < 8; ++j) o[j] = T[c8 + j][d];
    *reinterpret_cast<short8*>(dst + (size_t)d * 1024 + c8) = o;
  }
}

// ---------------- fused flash attention v11: KVBLK=128 outer tiles (two 64-key
// halves per barrier) -> 8 barriers instead of 16. 8-wave blocks (256 q-rows),
// raw exp2, static softmax + MFMA row-sums, reg-staged dbuf K/V slots ----------
__global__ __launch_bounds__(512) void attn11_kernel(
    const u16* __restrict__ qkv, const u16* __restrict__ vt, u16* __restrict__ z)
{
  constexpr int KLD = 72;            // K slot: [128 keys][64 d], stride 72
  constexpr int VLD = 136;           // V slot: [64 d][128 keys], stride 136
  constexpr int KSLOT = 128 * KLD;
  constexpr int VSLOT = 64 * VLD;
  __shared__ u16 Ks[2 * KSLOT];      // 36.9 KB
  __shared__ u16 Vs[2 * VSLOT];      // 34.8 KB   (total 71.7 KB -> 2 blocks/CU)

  const int tid = threadIdx.x;
  const int lane = tid & 63, w = tid >> 6;    // w = 0..7
  const int l31 = lane & 31, hi = lane >> 5;

  const int idx = blockIdx.x;
  const int head = idx % 192;        // all 4 q-blocks of a head share idx%8 -> same XCD
  const int qt   = idx / 192;        // 0..3
  const int b = head / 12, h = head % 12;

  const size_t rowbase = (size_t)b * 1024;
  const u16* Qp  = qkv + rowbase * 2304 + h * 64;
  const u16* Kp  = Qp + 768;
  const u16* Vtp = vt + (size_t)head * 64 * 1024;

  const int q0 = qt * 256 + w * 32;

  short8 qf[4];
#pragma unroll
  for (int c = 0; c < 4; ++c)
    qf[c] = *reinterpret_cast<const short8*>(
        Qp + (size_t)(q0 + l31) * 2304 + c * 16 + hi * 8);

  union { unsigned u[4]; short8 v; } ONE;
#pragma unroll
  for (int i = 0; i < 4; ++i) ONE.u[i] = 0x3F803F80u;
  const short8 ones = ONE.v;

  // staging: K 128x64 (rows tid>>3, +64; chunk (tid&7)*8);
  //          V^T 64x128 (rows tid>>4, +32; chunk (tid&15)*8)
  const int kr = tid >> 3, kc = (tid & 7) * 8;
  const int vr = tid >> 4, vc = (tid & 15) * 8;
  const u16* kstage = Kp + (size_t)kr * 2304 + kc;
  const u16* vstage = Vtp + (size_t)vr * 1024 + vc;
  constexpr size_t KADV = (size_t)128 * 2304;   // next 128 keys
  constexpr size_t VADV = 128;

  u16* const ksw = &Ks[kr * KLD + kc];
  u16* const vsw = &Vs[vr * VLD + vc];
  const u16* const ks0 = &Ks[l31 * KLD + hi * 8];
  const u16* const vs0 = &Vs[l31 * VLD + hi * 8];

  // prologue: outer tile 0 into regs (2 K pieces + 2 V pieces)
  short8 kvr0 = *reinterpret_cast<const short8*>(kstage);
  short8 kvr1 = *reinterpret_cast<const short8*>(kstage + (size_t)64 * 2304);
  short8 vvr0 = *reinterpret_cast<const short8*>(vstage);
  short8 vvr1 = *reinterpret_cast<const short8*>(vstage + (size_t)32 * 1024);
  kstage += KADV; vstage += VADV;

  floatx16 oacc0 = {}, oacc1 = {}, lacc = {};

  for (int kt = 0; kt < 8; ++kt) {
    const int ko = (kt & 1) * KSLOT;
    const int vo = (kt & 1) * VSLOT;
    // publish outer tile kt; safe: slot last read at tile kt-2, all waves passed
    // tile kt-1's barrier (after those reads) before this write.
    *reinterpret_cast<short8*>(ksw + ko)            = kvr0;
    *reinterpret_cast<short8*>(ksw + ko + 64 * KLD) = kvr1;
    *reinterpret_cast<short8*>(vsw + vo)            = vvr0;
    *reinterpret_cast<short8*>(vsw + vo + 32 * VLD) = vvr1;
    __syncthreads();               // ONE barrier per 128 keys

    if (kt < 7) {                  // issue next outer tile's loads; land during compute
      kvr0 = *reinterpret_cast<const short8*>(kstage);
      kvr1 = *reinterpret_cast<const short8*>(kstage + (size_t)64 * 2304);
      vvr0 = *reinterpret_cast<const short8*>(vstage);
      vvr1 = *reinterpret_cast<const short8*>(vstage + (size_t)32 * 1024);
      kstage += KADV; vstage += VADV;
    }

#pragma unroll
    for (int kb = 0; kb < 2; ++kb) {   // two sequential 64-key halves
      const u16* ka = ks0 + ko + kb * 64 * KLD;   // keys kb*64 + 0..63
      const u16* va = vs0 + vo + kb * 64;         // same keys as columns

      // S(key, q)
      floatx16 s0 = {}, s1 = {};
      __builtin_amdgcn_s_setprio(1);
#pragma unroll
      for (int c = 0; c < 4; ++c) {
        short8 kf0 = *reinterpret_cast<const short8*>(ka + c * 16);
        short8 kf1 = *reinterpret_cast<const short8*>(ka + 32 * KLD + c * 16);
        s0 = __builtin_amdgcn_mfma_f32_32x32x16_bf16(kf0, qf[c], s0, 0, 0, 0);
        s1 = __builtin_amdgcn_mfma_f32_32x32x16_bf16(kf1, qf[c], s1, 0, 0, 0);
      }
      __builtin_amdgcn_s_setprio(0);

      // p = 2^s (static softmax; s already in log2 units)
#pragma unroll
      for (int r = 0; r < 16; ++r) {
        s0[r] = fexp2(s0[r]);
        s1[r] = fexp2(s1[r]);
      }

      // P -> bf16 A-frags: cvt_pk + v_permlane32_swap (s_nop-guarded)
      short8 pa[4];
#pragma unroll
      for (int c = 0; c < 4; ++c) {
        const floatx16& sv = (c >> 1) ? s1 : s0;
        const int B0 = (c & 1) * 8, B1 = B0 + 4;
        unsigned x0 = cvt_pk_bf16(sv[B0],     sv[B0 + 1]);
        unsigned x1 = cvt_pk_bf16(sv[B0 + 2], sv[B0 + 3]);
        unsigned y0 = cvt_pk_bf16(sv[B1],     sv[B1 + 1]);
        unsigned y1 = cvt_pk_bf16(sv[B1 + 2], sv[B1 + 3]);
        asm("s_nop 1\n\tv_permlane32_swap_b32 %0, %1" : "+v"(x0), "+v"(y0));
        asm("s_nop 1\n\tv_permlane32_swap_b32 %0, %1" : "+v"(x1), "+v"(y1));
        union { unsigned u[4]; short8 v; } P;
        P.u[0] = x0; P.u[1] = x1; P.u[2] = y0; P.u[3] = y1;
        pa[c] = P.v;
      }

      // O += P @ V ; l += P @ 1
      __builtin_amdgcn_s_setprio(1);
#pragma unroll
      for (int c = 0; c < 4; ++c) {
        short8 vf0 = *reinterpret_cast<const short8*>(va + c * 16);
        short8 vf1 = *reinterpret_cast<const short8*>(va + 32 * VLD + c * 16);
        oacc0 = __builtin_amdgcn_mfma_f32_32x32x16_bf16(pa[c], vf0, oacc0, 0, 0, 0);
        oacc1 = __builtin_amdgcn_mfma_f32_32x32x16_bf16(pa[c], vf1, oacc1, 0, 0, 0);
        lacc  = __builtin_amdgcn_mfma_f32_32x32x16_bf16(pa[c], ones, lacc, 0, 0, 0);
      }
      __builtin_amdgcn_s_setprio(0);
    }
  }

  // epilogue: out = oacc / lacc (identical lane layout)
#pragma unroll
  for (int r = 0; r < 16; ++r) {
    int q = (r & 3) + 8 * (r >> 2) + 4 * hi;
    float li = frcp(lacc[r]);
    size_t orow = (rowbase + q0 + q) * (size_t)768 + h * 64;
    z[orow + l31]      = f2bf(oacc0[r] * li);
    z[orow + 32 + l31] = f2bf(oacc1[r] * li);
  }
}

extern "C" void kernel_launch(void* const* d_in, const int* in_sizes, int n_in,
                              void* d_out, int out_size, void* d_ws, size_t ws_size,
                              hipStream_t stream) {
  (void)in_sizes; (void)n_in; (void)out_size; (void)ws_size;
  const float* x      = (const float*)d_in[0];
  const float* w_qkv  = (const float*)d_in[1];
  const float* b_qkv  = (const float*)d_in[2];
  const float* w_proj = (const float*)d_in[3];
  const float* b_proj = (const float*)d_in[4];
  float* out = (float*)d_out;

  const int BS = 16 * 1024;  // B*S rows
  const int D = 768, N3 = 2304;
  const float QSC = 0.180336880f;    // 0.125 * log2(e)

  u16* xb  = (u16*)d_ws;                     // [BS, D]   (reused as vt after gemm1)
  u16* wqb = xb  + (size_t)BS * D;           // [N3, D]
  u16* wpb = wqb + (size_t)N3 * D;           // [D, D]
  u16* qkv = wpb + (size_t)D * D;            // [BS, N3]
  u16* zb  = qkv + (size_t)BS * N3;          // [BS, D]
  u16* vtb = xb;                             // aliases xb

  cvt3_kernel<<<2048, 256, 0, stream>>>(x, xb, BS * D / 4,
                                        w_qkv, wqb, N3 * D / 4,
                                        w_proj, wpb, D * D / 4);

  gemm_bt256_8p<false><<<(BS / 256) * (N3 / 256), 512, 0, stream>>>(
      xb, wqb, b_qkv, qkv, BS, N3, D, 768, QSC);
  vtrans_kernel<<<192 * 16, 256, 0, stream>>>(qkv, vtb);
  attn11_kernel<<<192 * 4, 512, 0, stream>>>(qkv, vtb, zb);
  gemm_bt256_8p<true><<<(BS / 256) * (D / 256), 512, 0, stream>>>(
      zb, wpb, b_proj, out, BS, D, D, 0, 1.0f);
}

// Round 20
// 208.605 us; speedup vs baseline: 1.0169x; 1.0169x over previous
//
#include <hip/hip_runtime.h>
#include <hip/hip_bf16.h>
#include <cstdint>
#include <cstddef>

typedef __attribute__((ext_vector_type(8))) short short8;
typedef __attribute__((ext_vector_type(4))) float floatx4;
typedef __attribute__((ext_vector_type(16))) float floatx16;
typedef unsigned short u16;

__device__ __forceinline__ u16 f2bf(float f) {
  unsigned u = __float_as_uint(f);
  u += 0x7FFFu + ((u >> 16) & 1u);
  return (u16)(u >> 16);
}

__device__ __forceinline__ unsigned cvt_pk_bf16(float a, float b) {
  unsigned r;
  asm("v_cvt_pk_bf16_f32 %0, %1, %2" : "=v"(r) : "v"(a), "v"(b));
  return r;
}

// raw 2^x. TRANS op: builtin so the compiler handles the TRANS->VALU hazard.
__device__ __forceinline__ float fexp2(float x) {
#if __has_builtin(__builtin_amdgcn_exp2f)
  return __builtin_amdgcn_exp2f(x);
#else
  float r;
  asm("v_exp_f32 %0, %1\n\ts_nop 1" : "=v"(r) : "v"(x));
  return r;
#endif
}

__device__ __forceinline__ float frcp(float x) {
#if __has_builtin(__builtin_amdgcn_rcpf)
  return __builtin_amdgcn_rcpf(x);
#else
  float r;
  asm("v_rcp_f32 %0, %1\n\ts_nop 1" : "=v"(r) : "v"(x));
  return r;
#endif
}

// async global -> LDS, 16B per lane. LDS dest = wave-uniform base + lane*16.
__device__ __forceinline__ void gload16(const u16* g, u16* l) {
  __builtin_amdgcn_global_load_lds(
      (const __attribute__((address_space(1))) void*)g,
      (__attribute__((address_space(3))) void*)l, 16, 0, 0);
}

__device__ __forceinline__ void phase_barrier() {
  __builtin_amdgcn_sched_barrier(0);
  __builtin_amdgcn_s_barrier();
  __builtin_amdgcn_sched_barrier(0);
}

#define MFMA16(a, b, c) __builtin_amdgcn_mfma_f32_16x16x32_bf16((a), (b), (c), 0, 0, 0)

// ---------------- f32 -> bf16 convert: 3 buffers in one launch ----------------
__global__ void cvt3_kernel(const float* __restrict__ a, u16* __restrict__ oa, int na4,
                            const float* __restrict__ b, u16* __restrict__ ob, int nb4,
                            const float* __restrict__ c, u16* __restrict__ oc, int nc4) {
  int i = blockIdx.x * blockDim.x + threadIdx.x;
  int stride = gridDim.x * blockDim.x;
  int ntot = na4 + nb4 + nc4;
  for (int idx = i; idx < ntot; idx += stride) {
    const float* src; u16* dst; int j = idx;
    if (j < na4)            { src = a; dst = oa; }
    else if (j < na4 + nb4) { src = b; dst = ob; j -= na4; }
    else                    { src = c; dst = oc; j -= na4 + nb4; }
    float4 v = reinterpret_cast<const float4*>(src)[j];
    ushort4 o = make_ushort4(f2bf(v.x), f2bf(v.y), f2bf(v.z), f2bf(v.w));
    reinterpret_cast<ushort4*>(dst)[j] = o;
  }
}

// ------ C = A @ B^T + bias, 256x256 tile, BK=64, 8-phase schedule (R16/R18 best) ------
template<bool OUTF32>
__global__ __launch_bounds__(512) void gemm_bt256_8p(
    const u16* __restrict__ A, const u16* __restrict__ B,
    const float* __restrict__ bias, void* __restrict__ Cout,
    int M, int N, int K, int qcols, float qscale)
{
  __shared__ u16 As[4 * 8192];   // 64 KB: [slot][half] 128x64
  __shared__ u16 Bs[4 * 8192];   // 64 KB
  const int tid = threadIdx.x;
  const int lane = tid & 63, w = tid >> 6;          // 8 waves
  const int l15 = lane & 15, lhi = lane >> 4;
  const int wm = w >> 2, wn = w & 3;                // 2M x 4N, wave tile 128x64

  const int mblocks = M >> 8;        // %8 == 0
  const int nb = N >> 8;
  const int bid = blockIdx.x;
  const int xcd = bid & 7;
  const int local = bid >> 3;
  const int mpx = mblocks >> 3;
  const int m0 = (xcd * mpx + local / nb) << 8;
  const int n0 = (local % nb) << 8;

  const int trow = tid >> 3;                         // 0..63
  const int cg8 = ((tid & 7) ^ ((tid >> 4) & 7)) * 8;  // swizzled 8-elem chunk
  const u16* aS = A + (size_t)(m0 + trow) * K + cg8;
  const u16* bS = B + (size_t)(n0 + trow) * K + cg8;
  const int ksteps = K >> 6;   // BK = 64

  const int x7 = (l15 >> 1) & 7;
  const int ko0 = l15 * 64 + (lhi ^ x7) * 8;        // kk = 0
  const int ko1 = l15 * 64 + ((4 + lhi) ^ x7) * 8;  // kk = 1
  const int brow = (wn & 1) * 64;                   // band within B region

  floatx4 acc[8][4] = {};

#define STG(matS, lds, v, h) do { \
    gload16((matS) + (size_t)((h) * 128) * K + (size_t)(v) * 64, \
            (lds) + ((((v) & 1) * 2 + (h)) * 8192) + w * 512); \
    gload16((matS) + (size_t)((h) * 128 + 64) * K + (size_t)(v) * 64, \
            (lds) + ((((v) & 1) * 2 + (h)) * 8192) + 4096 + w * 512); \
  } while (0)

  STG(aS, As, 0, 0); STG(aS, As, 0, 1);
  STG(bS, Bs, 0, 0); STG(bS, Bs, 0, 1);
  if (ksteps > 1) {
    STG(bS, Bs, 1, 0); STG(bS, Bs, 1, 1);
    asm volatile("s_waitcnt vmcnt(4)" ::: "memory");   // tile 0 resident
  } else {
    asm volatile("s_waitcnt vmcnt(0)" ::: "memory");
  }
  phase_barrier();

  for (int u = 0; u < ksteps; ++u) {
    const int so = (u & 1) * 16384;
    const u16* Ab = As + so + wm * 8192;
    const u16* Bb = Bs + so + (wn >> 1) * 8192;
    short8 af[4][2], bf[4][2];

    // ---- phase 1 (qm=0,qn=0): read af[0..3], bf[0..1]; stage A.h0(u+1)
#pragma unroll
    for (int i = 0; i < 4; ++i) {
      af[i][0] = *reinterpret_cast<const short8*>(Ab + (i * 16) * 64 + ko0);
      af[i][1] = *reinterpret_cast<const short8*>(Ab + (i * 16) * 64 + ko1);
    }
#pragma unroll
    for (int j = 0; j < 2; ++j) {
      bf[j][0] = *reinterpret_cast<const short8*>(Bb + (brow + j * 16) * 64 + ko0);
      bf[j][1] = *reinterpret_cast<const short8*>(Bb + (brow + j * 16) * 64 + ko1);
    }
    if (u + 1 < ksteps) STG(aS, As, u + 1, 0);
    phase_barrier();
    __builtin_amdgcn_s_setprio(1);
#pragma unroll
    for (int i = 0; i < 4; ++i)
#pragma unroll
      for (int j = 0; j < 2; ++j) {
        acc[i][j] = MFMA16(af[i][0], bf[j][0], acc[i][j]);
        acc[i][j] = MFMA16(af[i][1], bf[j][1], acc[i][j]);
      }
    __builtin_amdgcn_s_setprio(0);
    phase_barrier();

    // ---- phase 2 (qm=0,qn=1): read bf[2..3]; stage A.h1(u+1)
#pragma unroll
    for (int j = 2; j < 4; ++j) {
      bf[j][0] = *reinterpret_cast<const short8*>(Bb + (brow + 32 + (j - 2) * 16) * 64 + ko0);
      bf[j][1] = *reinterpret_cast<const short8*>(Bb + (brow + 32 + (j - 2) * 16) * 64 + ko1);
    }
    if (u + 1 < ksteps) STG(aS, As, u + 1, 1);
    phase_barrier();
    __builtin_amdgcn_s_setprio(1);
#pragma unroll
    for (int i = 0; i < 4; ++i)
#pragma unroll
      for (int j = 2; j < 4; ++j) {
        acc[i][j] = MFMA16(af[i][0], bf[j][0], acc[i][j]);
        acc[i][j] = MFMA16(af[i][1], bf[j][1], acc[i][j]);
      }
    __builtin_amdgcn_s_setprio(0);
    phase_barrier();

    // ---- phase 3 (qm=1,qn=0): read af rows 64..127; stage B.h0(u+2)
#pragma unroll
    for (int i = 0; i < 4; ++i) {
      af[i][0] = *reinterpret_cast<const short8*>(Ab + (64 + i * 16) * 64 + ko0);
      af[i][1] = *reinterpret_cast<const short8*>(Ab + (64 + i * 16) * 64 + ko1);
    }
    if (u + 2 < ksteps) STG(bS, Bs, u + 2, 0);
    phase_barrier();
    __builtin_amdgcn_s_setprio(1);
#pragma unroll
    for (int i = 0; i < 4; ++i)
#pragma unroll
      for (int j = 0; j < 2; ++j) {
        acc[4 + i][j] = MFMA16(af[i][0], bf[j][0], acc[4 + i][j]);
        acc[4 + i][j] = MFMA16(af[i][1], bf[j][1], acc[4 + i][j]);
      }
    __builtin_amdgcn_s_setprio(0);
    phase_barrier();

    // ---- phase 4 (qm=1,qn=1): stage B.h1(u+2); boundary vmcnt
    if (u + 2 < ksteps) STG(bS, Bs, u + 2, 1);
    phase_barrier();
    __builtin_amdgcn_s_setprio(1);
#pragma unroll
    for (int i = 0; i < 4; ++i)
#pragma unroll
      for (int j = 2; j < 4; ++j) {
        acc[4 + i][j] = MFMA16(af[i][0], bf[j][0], acc[4 + i][j]);
        acc[4 + i][j] = MFMA16(af[i][1], bf[j][1], acc[4 + i][j]);
      }
    __builtin_amdgcn_s_setprio(0);
    if (u + 1 < ksteps) {
      if (u + 2 < ksteps) asm volatile("s_waitcnt vmcnt(4)" ::: "memory");
      else                asm volatile("s_waitcnt vmcnt(0)" ::: "memory");
    }
    phase_barrier();
  }
#undef STG

#pragma unroll
  for (int i = 0; i < 8; ++i)
#pragma unroll
    for (int j = 0; j < 4; ++j) {
      int row = m0 + wm * 128 + i * 16 + lhi * 4;
      int col = n0 + wn * 64 + j * 16 + l15;
      float bv = bias[col];
      float sc = (col < qcols) ? qscale : 1.0f;
#pragma unroll
      for (int r = 0; r < 4; ++r) {
        float v = (acc[i][j][r] + bv) * sc;
        if (OUTF32) reinterpret_cast<float*>(Cout)[(size_t)(row + r) * N + col] = v;
        else        reinterpret_cast<u16*>(Cout)[(size_t)(row + r) * N + col] = f2bf(v);
      }
    }
}

// ---------------- V transpose: qkv V-part -> vt[(b*12+h)*64 + d][s] ----------------
__global__ __launch_bounds__(256) void vtrans_kernel(
    const u16* __restrict__ qkv, u16* __restrict__ vt)
{
  __shared__ u16 T[64][72];
  const int idx = blockIdx.x;
  const int st = idx & 15;
  const int bh = idx >> 4;
  const int b = bh / 12, h = bh % 12;
  const int t = threadIdx.x;
  const int r2 = t >> 3, c8 = (t & 7) * 8;

  const u16* src = qkv + ((size_t)(b * 1024 + st * 64)) * 2304 + 1536 + h * 64;
#pragma unroll
  for (int rr = 0; rr < 2; ++rr) {
    int s = rr * 32 + r2;
    short8 v = *reinterpret_cast<const short8*>(src + (size_t)s * 2304 + c8);
    *reinterpret_cast<short8*>(&T[s][c8]) = v;
  }
  __syncthreads();
  u16* dst = vt + (size_t)bh * 64 * 1024 + st * 64;
#pragma unroll
  for (int rr = 0; rr < 2; ++rr) {
    int d = rr * 32 + r2;
    short8 o;
#pragma unroll
    for (int j = 0; j < 8; ++j) o[j] = T[c8 + j][d];
    *reinterpret_cast<short8*>(dst + (size_t)d * 1024 + c8) = o;
  }
}

// ---------------- fused flash attention v9: dbuf K/V slots, ONE barrier/tile,
// 8-wave blocks (256 q-rows), raw exp2, static softmax + MFMA row-sums ----------
__global__ __launch_bounds__(512) void attn9_kernel(
    const u16* __restrict__ qkv, const u16* __restrict__ vt, u16* __restrict__ z)
{
  constexpr int LDK = 72;
  constexpr int SLOT = 64 * LDK;
  __shared__ u16 Ks[2 * SLOT];   // [slot][key][d]
  __shared__ u16 Vs[2 * SLOT];   // [slot][d][key]

  const int tid = threadIdx.x;
  const int lane = tid & 63, w = tid >> 6;    // w = 0..7
  const int l31 = lane & 31, hi = lane >> 5;

  const int idx = blockIdx.x;
  const int head = idx % 192;        // all 4 q-blocks of a head share idx%8 -> same XCD
  const int qt   = idx / 192;        // 0..3
  const int b = head / 12, h = head % 12;

  const size_t rowbase = (size_t)b * 1024;
  const u16* Qp  = qkv + rowbase * 2304 + h * 64;
  const u16* Kp  = Qp + 768;
  const u16* Vtp = vt + (size_t)head * 64 * 1024;

  const int q0 = qt * 256 + w * 32;

  short8 qf[4];
#pragma unroll
  for (int c = 0; c < 4; ++c)
    qf[c] = *reinterpret_cast<const short8*>(
        Qp + (size_t)(q0 + l31) * 2304 + c * 16 + hi * 8);

  union { unsigned u[4]; short8 v; } ONE;
#pragma unroll
  for (int i = 0; i < 4; ++i) ONE.u[i] = 0x3F803F80u;
  const short8 ones = ONE.v;

  const int srow = tid >> 3, scol = (tid & 7) * 8;

  const u16* kstage = Kp + (size_t)srow * 2304 + scol;
  const u16* vstage = Vtp + (size_t)srow * 1024 + scol;
  constexpr size_t KADV = (size_t)64 * 2304;
  constexpr size_t VADV = 64;

  u16* const ksw = &Ks[srow * LDK + scol];
  u16* const vsw = &Vs[srow * LDK + scol];
  const u16* const ks0 = &Ks[l31 * LDK + hi * 8];
  const u16* const vs0 = &Vs[l31 * LDK + hi * 8];

  // prologue: tile 0 into regs
  short8 kvr = *reinterpret_cast<const short8*>(kstage);
  short8 vvr = *reinterpret_cast<const short8*>(vstage);
  kstage += KADV; vstage += VADV;

  floatx16 oacc0 = {}, oacc1 = {}, lacc = {};

  for (int kt = 0; kt < 16; ++kt) {
    const int so = (kt & 1) * SLOT;
    // publish tile kt into slot kt&1; safe: slot last read in iter kt-2, and all
    // waves passed iter kt-1's barrier (after those reads) before this write.
    *reinterpret_cast<short8*>(ksw + so) = kvr;
    *reinterpret_cast<short8*>(vsw + so) = vvr;
    __syncthreads();               // slot kt&1 visible

    if (kt < 15) {                 // issue next tile's loads; land during compute
      kvr = *reinterpret_cast<const short8*>(kstage);
      vvr = *reinterpret_cast<const short8*>(vstage);
      kstage += KADV; vstage += VADV;
    }

    const u16* ka = ks0 + so;
    const u16* va = vs0 + so;

    // S(key, q)
    floatx16 s0 = {}, s1 = {};
    __builtin_amdgcn_s_setprio(1);
#pragma unroll
    for (int c = 0; c < 4; ++c) {
      short8 kf0 = *reinterpret_cast<const short8*>(ka + c * 16);
      short8 kf1 = *reinterpret_cast<const short8*>(ka + 32 * LDK + c * 16);
      s0 = __builtin_amdgcn_mfma_f32_32x32x16_bf16(kf0, qf[c], s0, 0, 0, 0);
      s1 = __builtin_amdgcn_mfma_f32_32x32x16_bf16(kf1, qf[c], s1, 0, 0, 0);
    }
    __builtin_amdgcn_s_setprio(0);

    // p = 2^s (static softmax; s already in log2 units)
#pragma unroll
    for (int r = 0; r < 16; ++r) {
      s0[r] = fexp2(s0[r]);
      s1[r] = fexp2(s1[r]);
    }

    // P -> bf16 A-frags: cvt_pk + v_permlane32_swap (s_nop-guarded)
    short8 pa[4];
#pragma unroll
    for (int c = 0; c < 4; ++c) {
      const floatx16& sv = (c >> 1) ? s1 : s0;
      const int B0 = (c & 1) * 8, B1 = B0 + 4;
      unsigned x0 = cvt_pk_bf16(sv[B0],     sv[B0 + 1]);
      unsigned x1 = cvt_pk_bf16(sv[B0 + 2], sv[B0 + 3]);
      unsigned y0 = cvt_pk_bf16(sv[B1],     sv[B1 + 1]);
      unsigned y1 = cvt_pk_bf16(sv[B1 + 2], sv[B1 + 3]);
      asm("s_nop 1\n\tv_permlane32_swap_b32 %0, %1" : "+v"(x0), "+v"(y0));
      asm("s_nop 1\n\tv_permlane32_swap_b32 %0, %1" : "+v"(x1), "+v"(y1));
      union { unsigned u[4]; short8 v; } P;
      P.u[0] = x0; P.u[1] = x1; P.u[2] = y0; P.u[3] = y1;
      pa[c] = P.v;
    }

    // O += P @ V ; l += P @ 1
    __builtin_amdgcn_s_setprio(1);
#pragma unroll
    for (int c = 0; c < 4; ++c) {
      short8 vf0 = *reinterpret_cast<const short8*>(va + c * 16);
      short8 vf1 = *reinterpret_cast<const short8*>(va + 32 * LDK + c * 16);
      oacc0 = __builtin_amdgcn_mfma_f32_32x32x16_bf16(pa[c], vf0, oacc0, 0, 0, 0);
      oacc1 = __builtin_amdgcn_mfma_f32_32x32x16_bf16(pa[c], vf1, oacc1, 0, 0, 0);
      lacc  = __builtin_amdgcn_mfma_f32_32x32x16_bf16(pa[c], ones, lacc, 0, 0, 0);
    }
    __builtin_amdgcn_s_setprio(0);
  }

  // epilogue: out = oacc / lacc (identical lane layout)
#pragma unroll
  for (int r = 0; r < 16; ++r) {
    int q = (r & 3) + 8 * (r >> 2) + 4 * hi;
    float li = frcp(lacc[r]);
    size_t orow = (rowbase + q0 + q) * (size_t)768 + h * 64;
    z[orow + l31]      = f2bf(oacc0[r] * li);
    z[orow + 32 + l31] = f2bf(oacc1[r] * li);
  }
}

extern "C" void kernel_launch(void* const* d_in, const int* in_sizes, int n_in,
                              void* d_out, int out_size, void* d_ws, size_t ws_size,
                              hipStream_t stream) {
  (void)in_sizes; (void)n_in; (void)out_size; (void)ws_size;
  const float* x      = (const float*)d_in[0];
  const float* w_qkv  = (const float*)d_in[1];
  const float* b_qkv  = (const float*)d_in[2];
  const float* w_proj = (const float*)d_in[3];
  const float* b_proj = (const float*)d_in[4];
  float* out = (float*)d_out;

  const int BS = 16 * 1024;  // B*S rows
  const int D = 768, N3 = 2304;
  const float QSC = 0.180336880f;    // 0.125 * log2(e)

  u16* xb  = (u16*)d_ws;                     // [BS, D]   (reused as vt after gemm1)
  u16* wqb = xb  + (size_t)BS * D;           // [N3, D]
  u16* wpb = wqb + (size_t)N3 * D;           // [D, D]
  u16* qkv = wpb + (size_t)D * D;            // [BS, N3]
  u16* zb  = qkv + (size_t)BS * N3;          // [BS, D]
  u16* vtb = xb;                             // aliases xb

  cvt3_kernel<<<2048, 256, 0, stream>>>(x, xb, BS * D / 4,
                                        w_qkv, wqb, N3 * D / 4,
                                        w_proj, wpb, D * D / 4);

  gemm_bt256_8p<false><<<(BS / 256) * (N3 / 256), 512, 0, stream>>>(
      xb, wqb, b_qkv, qkv, BS, N3, D, 768, QSC);
  vtrans_kernel<<<192 * 16, 256, 0, stream>>>(qkv, vtb);
  attn9_kernel<<<192 * 4, 512, 0, stream>>>(qkv, vtb, zb);
  gemm_bt256_8p<true><<<(BS / 256) * (D / 256), 512, 0, stream>>>(
      zb, wpb, b_proj, out, BS, D, D, 0, 1.0f);
}